// Round 8
// baseline (257.410 us; speedup 1.0000x reference)
//
#include <hip/hip_runtime.h>
#include <hip/hip_bf16.h>
#include <math.h>

typedef __bf16 bf16x8 __attribute__((ext_vector_type(8)));
typedef float f32x4 __attribute__((ext_vector_type(4)));

#define CDIM 128

__global__ void sentinel_kernel(float* outf) {
  if (threadIdx.x == 0) outf[0] = 12345.0f;  // ws_size too small signature
}

// ---------------- prep + hist fused (deg pre-zeroed by hipMemsetAsync) -------
// blocks [0,48): wt[v][r][kb][o][j] = w_v[r][kb*8+j][o]
// block 48: c = le.e consts
// blocks [49,...): hist atomics, 4 edges/thread
__global__ __launch_bounds__(256) void prep_hist_kernel(
    const float* __restrict__ w1, const float* __restrict__ w2,
    __hip_bfloat16* __restrict__ wt,
    const float* __restrict__ le1, const float* __restrict__ e1,
    const float* __restrict__ le2, const float* __restrict__ e2,
    float* __restrict__ outc, const int* __restrict__ dstv,
    int* __restrict__ deg, int perW, int E) {
  const int b = blockIdx.x;
  const int tid = threadIdx.x;
  if (b < 48) {
    int t = b * 256 + tid;
    if (t >= perW * 2) return;
    const float* w = (t < perW) ? w1 : w2;
    int tt = (t < perW) ? t : t - perW;
    int r = tt >> 11;
    int rem = tt & 2047;
    int kb = rem >> 7;
    int o = rem & 127;
    const float* wr = w + ((size_t)r << 14);
    union { __hip_bfloat16 h[8]; int4 v; } u;
#pragma unroll
    for (int j = 0; j < 8; ++j)
      u.h[j] = __float2bfloat16(wr[(size_t)(kb * 8 + j) * CDIM + o]);
    *reinterpret_cast<int4*>(wt + (size_t)t * 8) = u.v;
  } else if (b == 48) {
    if (tid < 64) {
      float v1 = le1[tid] * e1[tid] + le1[tid + 64] * e1[tid + 64];
      float v2 = le2[tid] * e2[tid] + le2[tid + 64] * e2[tid + 64];
#pragma unroll
      for (int off = 32; off > 0; off >>= 1) {
        v1 += __shfl_xor(v1, off, 64);
        v2 += __shfl_xor(v2, off, 64);
      }
      if (tid == 0) { outc[0] = v1; outc[1] = v2; }
    }
  } else {
    int e0 = (b - 49) * 1024 + tid * 4;
    if (e0 + 3 < E) {
      int4 d4 = *reinterpret_cast<const int4*>(&dstv[e0]);
      atomicAdd(&deg[d4.x], 1);
      atomicAdd(&deg[d4.y], 1);
      atomicAdd(&deg[d4.z], 1);
      atomicAdd(&deg[d4.w], 1);
    } else {
      for (int t = 0; t < 4; ++t) {
        int e = e0 + t;
        if (e < E) atomicAdd(&deg[dstv[e]], 1);
      }
    }
  }
}

// ---------------- CSR scans ----------------

__global__ __launch_bounds__(256) void scan1_kernel(const int* __restrict__ deg,
                                                    int* __restrict__ rowptr,
                                                    int* __restrict__ partials, int n) {
  __shared__ int sh[256];
  int t = threadIdx.x;
  int base = blockIdx.x * 1024;
  int idx = base + t * 4;
  int v[4]; int s = 0;
#pragma unroll
  for (int j = 0; j < 4; ++j) { v[j] = (idx + j < n) ? deg[idx + j] : 0; s += v[j]; }
  sh[t] = s;
  __syncthreads();
  for (int off = 1; off < 256; off <<= 1) {
    int x = (t >= off) ? sh[t - off] : 0;
    __syncthreads();
    sh[t] += x;
    __syncthreads();
  }
  int excl = sh[t] - s;
  if (t == 255) partials[blockIdx.x] = sh[255];
  int run = excl;
#pragma unroll
  for (int j = 0; j < 4; ++j) {
    if (idx + j < n) rowptr[idx + j] = run;
    run += v[j];
  }
}

// scan3 with inline prefix of partials (nb <= 64)
__global__ __launch_bounds__(256) void scan3_kernel(int* __restrict__ rowptr,
                                                    int* __restrict__ cursor,
                                                    const int* __restrict__ partials,
                                                    int nb, int n, int E) {
  __shared__ int spfx[64];
  int t = threadIdx.x;
  if (t < 64) {
    int pv = (t < nb) ? partials[t] : 0;
    int v = pv;
#pragma unroll
    for (int off = 1; off < 64; off <<= 1) {
      int u = __shfl_up(v, off, 64);
      if (t >= off) v += u;
    }
    spfx[t] = v - pv;  // exclusive prefix
  }
  __syncthreads();
  int i = blockIdx.x * 256 + t;
  if (i < n) {
    int v = rowptr[i] + spfx[i >> 10];
    rowptr[i] = v;
    cursor[i] = v;
  } else if (i == n) {
    rowptr[n] = E;
  }
}

// ---------------- scatter (standalone, 4 edges/thread) ----------------
__global__ __launch_bounds__(256) void scatter_kernel(
    const int* __restrict__ srcv, const int* __restrict__ dstv,
    const int* __restrict__ etype, const float* __restrict__ eattr,
    int* __restrict__ cursor, int2* __restrict__ kattr, int E, int n) {
  int e0 = blockIdx.x * 1024 + threadIdx.x * 4;
  if (e0 + 3 < E) {
    int4 s4 = *reinterpret_cast<const int4*>(&srcv[e0]);
    int4 d4 = *reinterpret_cast<const int4*>(&dstv[e0]);
    int4 t4 = *reinterpret_cast<const int4*>(&etype[e0]);
    float4 a4 = *reinterpret_cast<const float4*>(&eattr[e0]);
    int p0 = atomicAdd(&cursor[d4.x], 1);
    kattr[p0] = make_int2(t4.x * n + s4.x, __float_as_int(a4.x));
    int p1 = atomicAdd(&cursor[d4.y], 1);
    kattr[p1] = make_int2(t4.y * n + s4.y, __float_as_int(a4.y));
    int p2 = atomicAdd(&cursor[d4.z], 1);
    kattr[p2] = make_int2(t4.z * n + s4.z, __float_as_int(a4.z));
    int p3 = atomicAdd(&cursor[d4.w], 1);
    kattr[p3] = make_int2(t4.w * n + s4.w, __float_as_int(a4.w));
  } else {
    for (int t = 0; t < 4; ++t) {
      int e = e0 + t;
      if (e < E) {
        int p = atomicAdd(&cursor[dstv[e]], 1);
        kattr[p] = make_int2(etype[e] * n + srcv[e], __float_as_int(eattr[e]));
      }
    }
  }
}

// ---------------- GEMM body: 64 rows/block, 3-relation loop ------------------
// x rows read ONCE into registers (cross-block x sharing misses to memory);
// weight tile re-staged per relation (wt is 96KB, L2-resident).
// BF16IN: layer-2 input is bf16 (direct fragment load, no cvt).
// MFMA operands SWAPPED: acc = mfma(b, a) -> transposed C layout:
//   acc[ot][reg] = xw[m = tb*64+wave*16+c16][o = ot*16+quad*4+reg]
template <int BF16IN>
__device__ __forceinline__ void gemm_body64(
    int tb, const float* __restrict__ xf, const __hip_bfloat16* __restrict__ xb,
    const __hip_bfloat16* __restrict__ wt,
    const float* __restrict__ qv, const float* __restrict__ kv,
    __hip_bfloat16* __restrict__ xwout, float* __restrict__ sq,
    float* __restrict__ sk, int n, __hip_bfloat16* wlds, float* qls, float* kls) {
  const int tid = threadIdx.x;
  const int wave = tid >> 6, lane = tid & 63;
  const int quad = lane >> 4, c16 = lane & 15;
  const int m = tb * 64 + wave * 16 + c16;
  const bool ok = m < n;

  if (tid < 128) qls[tid] = qv[tid];
  else kls[tid - 128] = kv[tid - 128];

  bf16x8 zf;
#pragma unroll
  for (int j = 0; j < 8; ++j) zf[j] = (__bf16)0.0f;

  bf16x8 af[4];
#pragma unroll
  for (int ks = 0; ks < 4; ++ks) {
    if (ok) {
      if (BF16IN) {
        af[ks] = *reinterpret_cast<const bf16x8*>(
            xb + (size_t)m * CDIM + ks * 32 + quad * 8);
      } else {
        const float* xp = xf + (size_t)m * CDIM + ks * 32 + quad * 8;
        f32x4 x0 = *reinterpret_cast<const f32x4*>(xp);
        f32x4 x1 = *reinterpret_cast<const f32x4*>(xp + 4);
        bf16x8 a;
#pragma unroll
        for (int j = 0; j < 4; ++j) { a[j] = (__bf16)x0[j]; a[4 + j] = (__bf16)x1[j]; }
        af[ks] = a;
      }
    } else {
      af[ks] = zf;
    }
  }

  for (int r = 0; r < 3; ++r) {
    if (r) __syncthreads();  // previous relation's LDS reads done
    {
      const int4* src = reinterpret_cast<const int4*>(wt + ((size_t)r << 14));
      int4* dst = reinterpret_cast<int4*>(wlds);
#pragma unroll
      for (int i = 0; i < 8; ++i) dst[tid + i * 256] = src[tid + i * 256];
    }
    __syncthreads();

    f32x4 acc[8];
#pragma unroll
    for (int ot = 0; ot < 8; ++ot) acc[ot] = (f32x4){0.f, 0.f, 0.f, 0.f};

#pragma unroll
    for (int ks = 0; ks < 4; ++ks) {
#pragma unroll
      for (int ot = 0; ot < 8; ++ot) {
        bf16x8 b = *reinterpret_cast<const bf16x8*>(
            &wlds[(((ks * 4 + quad) * 128) + ot * 16 + c16) * 8]);
        acc[ot] = __builtin_amdgcn_mfma_f32_16x16x32_bf16(b, af[ks], acc[ot], 0, 0, 0);
      }
    }

    __hip_bfloat16* rp = xwout + (((size_t)r * n + m) << 7) + quad * 4;
    float s_q = 0.f, s_k = 0.f;
#pragma unroll
    for (int ot = 0; ot < 8; ++ot) {
      f32x4 a = acc[ot];
      f32x4 q4 = *reinterpret_cast<const f32x4*>(&qls[ot * 16 + quad * 4]);
      f32x4 k4 = *reinterpret_cast<const f32x4*>(&kls[ot * 16 + quad * 4]);
      s_q += a[0] * q4[0] + a[1] * q4[1] + a[2] * q4[2] + a[3] * q4[3];
      s_k += a[0] * k4[0] + a[1] * k4[1] + a[2] * k4[2] + a[3] * k4[3];
      if (ok) {
        union { __hip_bfloat16 b4[4]; uint2 u; } pk;
#pragma unroll
        for (int t = 0; t < 4; ++t) pk.b4[t] = __float2bfloat16(a[t]);
        *reinterpret_cast<uint2*>(rp + ot * 16) = pk.u;
      }
    }
    s_q += __shfl_xor(s_q, 16, 64);
    s_q += __shfl_xor(s_q, 32, 64);
    s_k += __shfl_xor(s_k, 16, 64);
    s_k += __shfl_xor(s_k, 32, 64);
    if (quad == 0 && ok) {
      sq[(size_t)r * n + m] = s_q;
      sk[(size_t)r * n + m] = s_k;
    }
  }
}

// layer 1: f32 input
__global__ __launch_bounds__(256) void gemm_xw_f32_kernel(
    const float* __restrict__ xin, const __hip_bfloat16* __restrict__ wt,
    const float* __restrict__ qv, const float* __restrict__ kv,
    __hip_bfloat16* __restrict__ xwout, float* __restrict__ sq, float* __restrict__ sk,
    int n) {
  __shared__ __hip_bfloat16 wlds[16 * 128 * 8];
  __shared__ float qls[128], kls[128];
  gemm_body64<0>(blockIdx.x, xin, nullptr, wt, qv, kv, xwout, sq, sk, n,
                 wlds, qls, kls);
}

// layer 2: bf16 input (hb)
__global__ __launch_bounds__(256) void gemm_xw_bf16_kernel(
    const __hip_bfloat16* __restrict__ xin, const __hip_bfloat16* __restrict__ wt,
    const float* __restrict__ qv, const float* __restrict__ kv,
    __hip_bfloat16* __restrict__ xwout, float* __restrict__ sq, float* __restrict__ sk,
    int n) {
  __shared__ __hip_bfloat16 wlds[16 * 128 * 8];
  __shared__ float qls[128], kls[128];
  gemm_body64<1>(blockIdx.x, nullptr, xin, wt, qv, kv, xwout, sq, sk, n,
                 wlds, qls, kls);
}

// ---------------- aggregation: one 16-lane group per node --------------------
// 4 nodes/wave, 16 nodes/block. den and acc lane-local (no reductions); all 16
// lanes write the output row. kattr double-buffered (kaA/kaB): next 4 edge
// descriptors prefetch while current 4 compute -> ~1 mem round-trip / 4 edges.
// OUTBF16: layer-1 path writes bf16 (+relu); layer-2 writes f32 (no relu).
template <int OUTBF16>
__global__ __launch_bounds__(256) void aggregate_kernel(
    const int* __restrict__ rowptr, const int2* __restrict__ kattr,
    const float* __restrict__ sq, const float* __restrict__ sk,
    const __hip_bfloat16* __restrict__ xw, const float* __restrict__ bias,
    const float* __restrict__ cscal, float* __restrict__ outf,
    __hip_bfloat16* __restrict__ outb, int n) {
  const int wave = threadIdx.x >> 6, lane = threadIdx.x & 63;
  const int g = lane >> 4;     // node slot within wave
  const int sub = lane & 15;   // 8-col chunk within node row
  const int node = blockIdx.x * 16 + wave * 4 + g;
  if (node >= n) return;       // per-group predication; no barriers below
  const float c = cscal[0];
  const int n2 = n * 2;

  const int start = rowptr[node];
  const int deg = rowptr[node + 1] - start;
  const float s0 = sq[node], s1 = sq[n + node], s2 = sq[n2 + node];

  float acc[8];
#pragma unroll
  for (int t = 0; t < 8; ++t) acc[t] = 0.f;
  float den = 0.f;

  if (deg > 0) {
    int2 kaA0, kaA1, kaA2, kaA3;
    kaA0 = kattr[start + (0 < deg ? 0 : 0)];
    kaA1 = kattr[start + (1 < deg ? 1 : 0)];
    kaA2 = kattr[start + (2 < deg ? 2 : 0)];
    kaA3 = kattr[start + (3 < deg ? 3 : 0)];
    for (int j0 = 0; j0 < deg; j0 += 4) {
      // prefetch next block (independent loads, overlap current compute)
      int nj = j0 + 4;
      int2 kaB0 = kattr[start + (nj + 0 < deg ? nj + 0 : 0)];
      int2 kaB1 = kattr[start + (nj + 1 < deg ? nj + 1 : 0)];
      int2 kaB2 = kattr[start + (nj + 2 < deg ? nj + 2 : 0)];
      int2 kaB3 = kattr[start + (nj + 3 < deg ? nj + 3 : 0)];

      int2 ka[4] = {kaA0, kaA1, kaA2, kaA3};
      float w[4];
      bf16x8 f[4];
#pragma unroll
      for (int t = 0; t < 4; ++t) {
        int kk = ka[t].x;
        float sv = (kk >= n2) ? s2 : ((kk >= n) ? s1 : s0);
        float l = sv + sk[kk] + c * __int_as_float(ka[t].y);
        l = l > 0.f ? l : 0.2f * l;
        w[t] = (j0 + t < deg) ? __expf(l) : 0.f;
        f[t] = *reinterpret_cast<const bf16x8*>(xw + ((size_t)kk << 7) + sub * 8);
      }
#pragma unroll
      for (int t = 0; t < 8; ++t)
        acc[t] += w[0] * (float)f[0][t] + w[1] * (float)f[1][t] +
                  w[2] * (float)f[2][t] + w[3] * (float)f[3][t];
      den += (w[0] + w[1]) + (w[2] + w[3]);

      kaA0 = kaB0; kaA1 = kaB1; kaA2 = kaB2; kaA3 = kaB3;
    }
  }

  float inv = 1.0f / (den + 1e-16f);
  f32x4 b0 = *reinterpret_cast<const f32x4*>(bias + sub * 8);
  f32x4 b1 = *reinterpret_cast<const f32x4*>(bias + sub * 8 + 4);
  f32x4 o0, o1;
#pragma unroll
  for (int t = 0; t < 4; ++t) {
    o0[t] = acc[t] * inv + b0[t];
    o1[t] = acc[4 + t] * inv + b1[t];
  }
  if (OUTBF16) {
    // relu + bf16 store (identical values to f32-store + later bf16 cvt)
    union { __hip_bfloat16 h[8]; int4 v; } pk;
#pragma unroll
    for (int t = 0; t < 4; ++t) {
      pk.h[t] = __float2bfloat16(fmaxf(o0[t], 0.f));
      pk.h[4 + t] = __float2bfloat16(fmaxf(o1[t], 0.f));
    }
    *reinterpret_cast<int4*>(outb + (size_t)node * CDIM + sub * 8) = pk.v;
  } else {
    float* op = outf + (size_t)node * CDIM + sub * 8;
    *reinterpret_cast<f32x4*>(op) = o0;
    *reinterpret_cast<f32x4*>(op + 4) = o1;
  }
}

// ---------------- launcher ----------------

extern "C" void kernel_launch(void* const* d_in, const int* in_sizes, int n_in,
                              void* d_out, int out_size, void* d_ws, size_t ws_size,
                              hipStream_t stream) {
  const float* x     = (const float*)d_in[0];
  const int*   eidx  = (const int*)d_in[1];
  const int*   etype = (const int*)d_in[2];
  const float* eattr = (const float*)d_in[3];
  const float* w1  = (const float*)d_in[4];
  const float* q1  = (const float*)d_in[5];
  const float* k1  = (const float*)d_in[6];
  const float* le1 = (const float*)d_in[7];
  const float* e1  = (const float*)d_in[8];
  const float* b1  = (const float*)d_in[9];
  const float* w2  = (const float*)d_in[10];
  const float* q2  = (const float*)d_in[11];
  const float* k2  = (const float*)d_in[12];
  const float* le2 = (const float*)d_in[13];
  const float* e2  = (const float*)d_in[14];
  const float* b2  = (const float*)d_in[15];

  const int N = in_sizes[0] / CDIM;           // 50000
  const int E = in_sizes[2];                  // 500000
  const int R = in_sizes[4] / (CDIM * CDIM);  // 3
  const int* srcv = eidx;
  const int* dstv = eidx + E;

  char* p = (char*)d_ws;
  auto alloc = [&](size_t bytes) -> void* {
    void* q = (void*)p;
    p += (bytes + 255) & ~(size_t)255;
    return q;
  };
  float* sq       = (float*)alloc((size_t)R * N * 4);
  float* sk       = (float*)alloc((size_t)R * N * 4);
  int*   deg      = (int*)alloc((size_t)N * 4);
  int*   rowptr   = (int*)alloc((size_t)(N + 1) * 4);
  int*   cursor   = (int*)alloc((size_t)N * 4);
  int*   partials = (int*)alloc(4096);
  int2*  kattr    = (int2*)alloc((size_t)E * 8);
  __hip_bfloat16* wt = (__hip_bfloat16*)alloc((size_t)2 * R * CDIM * CDIM * 2);
  float* cscal    = (float*)alloc(256);
  __hip_bfloat16* xw = (__hip_bfloat16*)alloc((size_t)R * N * CDIM * 2);
  __hip_bfloat16* hb = (__hip_bfloat16*)alloc((size_t)N * CDIM * 2);

  size_t needed = (size_t)(p - (char*)d_ws);
  if (needed > ws_size) {
    sentinel_kernel<<<1, 64, 0, stream>>>((float*)d_out);
    return;
  }

  float* outp = (float*)d_out;

  const int eg4 = (E + 1023) / 1024;          // 489 (4 edges/thread)
  const int nb = (N + 1023) / 1024;           // 49 (<=64 required by scan3 prefix)
  const int NT = (N + 63) / 64;               // 782 gemm tiles
  const int nodes16 = (N + 15) / 16;          // 3125 agg blocks
  const int perW = R * 2048;

  // 1) zero deg (stream-ordered, graph-capturable)
  hipMemsetAsync(deg, 0, (size_t)N * 4, stream);

  // 2) prep (wt transpose + consts) + hist, fused
  prep_hist_kernel<<<49 + eg4, 256, 0, stream>>>(w1, w2, wt, le1, e1, le2, e2,
                                                 cscal, dstv, deg, perW, E);

  // 3-4) CSR scans
  scan1_kernel<<<nb, 256, 0, stream>>>(deg, rowptr, partials, N);
  scan3_kernel<<<(N + 1 + 255) / 256, 256, 0, stream>>>(rowptr, cursor, partials, nb, N, E);

  // 5) scatter (standalone for per-kernel visibility)
  scatter_kernel<<<eg4, 256, 0, stream>>>(srcv, dstv, etype, eattr, cursor, kattr, E, N);

  // 6) gemm layer 1 (f32 input)
  gemm_xw_f32_kernel<<<NT, 256, 0, stream>>>(x, wt, q1, k1, xw, sq, sk, N);

  // 7) aggregate layer 1 -> bf16 hidden (relu)
  aggregate_kernel<1><<<nodes16, 256, 0, stream>>>(rowptr, kattr, sq, sk, xw, b1,
                                                   cscal + 0, nullptr, hb, N);

  // 8) gemm layer 2 (bf16 input)
  gemm_xw_bf16_kernel<<<NT, 256, 0, stream>>>(hb, wt + (size_t)R * CDIM * CDIM,
                                              q2, k2, xw, sq, sk, N);

  // 9) aggregate layer 2 -> f32 output
  aggregate_kernel<0><<<nodes16, 256, 0, stream>>>(rowptr, kattr, sq, sk, xw, b2,
                                                   cscal + 1, outp, nullptr, N);
}

// Round 9
// 239.829 us; speedup vs baseline: 1.0733x; 1.0733x over previous
//
#include <hip/hip_runtime.h>
#include <hip/hip_bf16.h>
#include <math.h>

typedef __bf16 bf16x8 __attribute__((ext_vector_type(8)));
typedef float f32x4 __attribute__((ext_vector_type(4)));

#define CDIM 128

__global__ void sentinel_kernel(float* outf) {
  if (threadIdx.x == 0) outf[0] = 12345.0f;  // ws_size too small signature
}

// ---------------- prep + hist fused (deg pre-zeroed by hipMemsetAsync) -------
// blocks [0,48): wt[v][r][kb][o][j] = w_v[r][kb*8+j][o]
// block 48: c = le.e consts
// blocks [49,...): hist atomics, 4 edges/thread
__global__ __launch_bounds__(256) void prep_hist_kernel(
    const float* __restrict__ w1, const float* __restrict__ w2,
    __hip_bfloat16* __restrict__ wt,
    const float* __restrict__ le1, const float* __restrict__ e1,
    const float* __restrict__ le2, const float* __restrict__ e2,
    float* __restrict__ outc, const int* __restrict__ dstv,
    int* __restrict__ deg, int perW, int E) {
  const int b = blockIdx.x;
  const int tid = threadIdx.x;
  if (b < 48) {
    int t = b * 256 + tid;
    if (t >= perW * 2) return;
    const float* w = (t < perW) ? w1 : w2;
    int tt = (t < perW) ? t : t - perW;
    int r = tt >> 11;
    int rem = tt & 2047;
    int kb = rem >> 7;
    int o = rem & 127;
    const float* wr = w + ((size_t)r << 14);
    union { __hip_bfloat16 h[8]; int4 v; } u;
#pragma unroll
    for (int j = 0; j < 8; ++j)
      u.h[j] = __float2bfloat16(wr[(size_t)(kb * 8 + j) * CDIM + o]);
    *reinterpret_cast<int4*>(wt + (size_t)t * 8) = u.v;
  } else if (b == 48) {
    if (tid < 64) {
      float v1 = le1[tid] * e1[tid] + le1[tid + 64] * e1[tid + 64];
      float v2 = le2[tid] * e2[tid] + le2[tid + 64] * e2[tid + 64];
#pragma unroll
      for (int off = 32; off > 0; off >>= 1) {
        v1 += __shfl_xor(v1, off, 64);
        v2 += __shfl_xor(v2, off, 64);
      }
      if (tid == 0) { outc[0] = v1; outc[1] = v2; }
    }
  } else {
    int e0 = (b - 49) * 1024 + tid * 4;
    if (e0 + 3 < E) {
      int4 d4 = *reinterpret_cast<const int4*>(&dstv[e0]);
      atomicAdd(&deg[d4.x], 1);
      atomicAdd(&deg[d4.y], 1);
      atomicAdd(&deg[d4.z], 1);
      atomicAdd(&deg[d4.w], 1);
    } else {
      for (int t = 0; t < 4; ++t) {
        int e = e0 + t;
        if (e < E) atomicAdd(&deg[dstv[e]], 1);
      }
    }
  }
}

// ---------------- CSR scans ----------------

__global__ __launch_bounds__(256) void scan1_kernel(const int* __restrict__ deg,
                                                    int* __restrict__ rowptr,
                                                    int* __restrict__ partials, int n) {
  __shared__ int sh[256];
  int t = threadIdx.x;
  int base = blockIdx.x * 1024;
  int idx = base + t * 4;
  int v[4]; int s = 0;
#pragma unroll
  for (int j = 0; j < 4; ++j) { v[j] = (idx + j < n) ? deg[idx + j] : 0; s += v[j]; }
  sh[t] = s;
  __syncthreads();
  for (int off = 1; off < 256; off <<= 1) {
    int x = (t >= off) ? sh[t - off] : 0;
    __syncthreads();
    sh[t] += x;
    __syncthreads();
  }
  int excl = sh[t] - s;
  if (t == 255) partials[blockIdx.x] = sh[255];
  int run = excl;
#pragma unroll
  for (int j = 0; j < 4; ++j) {
    if (idx + j < n) rowptr[idx + j] = run;
    run += v[j];
  }
}

// scan3 with inline prefix of partials (nb <= 64)
__global__ __launch_bounds__(256) void scan3_kernel(int* __restrict__ rowptr,
                                                    int* __restrict__ cursor,
                                                    const int* __restrict__ partials,
                                                    int nb, int n, int E) {
  __shared__ int spfx[64];
  int t = threadIdx.x;
  if (t < 64) {
    int pv = (t < nb) ? partials[t] : 0;
    int v = pv;
#pragma unroll
    for (int off = 1; off < 64; off <<= 1) {
      int u = __shfl_up(v, off, 64);
      if (t >= off) v += u;
    }
    spfx[t] = v - pv;  // exclusive prefix
  }
  __syncthreads();
  int i = blockIdx.x * 256 + t;
  if (i < n) {
    int v = rowptr[i] + spfx[i >> 10];
    rowptr[i] = v;
    cursor[i] = v;
  } else if (i == n) {
    rowptr[n] = E;
  }
}

// ---------------- GEMM body: 128 rows/block, 3-relation loop -----------------
// x rows read ONCE into registers; weight tile re-staged per relation
// (wt is 96KB, L2-resident). BF16IN: layer-2 input is bf16 (no cvt).
// MFMA operands SWAPPED: acc = mfma(b, a) -> transposed C layout:
//   acc[h][ot][reg] = xw[m = base+wave*32+h*16+c16][o = ot*16+quad*4+reg]
template <int BF16IN>
__device__ __forceinline__ void gemm_body128(
    int tileb, const float* __restrict__ xf, const __hip_bfloat16* __restrict__ xb,
    const __hip_bfloat16* __restrict__ wt,
    const float* __restrict__ qv, const float* __restrict__ kv,
    __hip_bfloat16* __restrict__ xwout, float* __restrict__ sq,
    float* __restrict__ sk, int n, __hip_bfloat16* wlds, float* qls, float* kls) {
  const int base = tileb * 128;
  const int tid = threadIdx.x;
  const int wave = tid >> 6, lane = tid & 63;
  const int quad = lane >> 4, c16 = lane & 15;

  if (tid < 128) qls[tid] = qv[tid];
  else kls[tid - 128] = kv[tid - 128];

  bf16x8 zf;
#pragma unroll
  for (int j = 0; j < 8; ++j) zf[j] = (__bf16)0.0f;

  bf16x8 af[2][4];
#pragma unroll
  for (int h = 0; h < 2; ++h) {
    int m = base + wave * 32 + h * 16 + c16;
#pragma unroll
    for (int ks = 0; ks < 4; ++ks) {
      if (m < n) {
        if (BF16IN) {
          af[h][ks] = *reinterpret_cast<const bf16x8*>(
              xb + (size_t)m * CDIM + ks * 32 + quad * 8);
        } else {
          const float* xp = xf + (size_t)m * CDIM + ks * 32 + quad * 8;
          f32x4 x0 = *reinterpret_cast<const f32x4*>(xp);
          f32x4 x1 = *reinterpret_cast<const f32x4*>(xp + 4);
          bf16x8 a;
#pragma unroll
          for (int j = 0; j < 4; ++j) { a[j] = (__bf16)x0[j]; a[4 + j] = (__bf16)x1[j]; }
          af[h][ks] = a;
        }
      } else {
        af[h][ks] = zf;
      }
    }
  }

  for (int r = 0; r < 3; ++r) {
    if (r) __syncthreads();  // previous relation's LDS reads done
    {
      const int4* src = reinterpret_cast<const int4*>(wt + ((size_t)r << 14));
      int4* dst = reinterpret_cast<int4*>(wlds);
#pragma unroll
      for (int i = 0; i < 8; ++i) dst[tid + i * 256] = src[tid + i * 256];
    }
    __syncthreads();

    f32x4 acc[2][8];
#pragma unroll
    for (int h = 0; h < 2; ++h)
#pragma unroll
      for (int ot = 0; ot < 8; ++ot) acc[h][ot] = (f32x4){0.f, 0.f, 0.f, 0.f};

#pragma unroll
    for (int ks = 0; ks < 4; ++ks) {
#pragma unroll
      for (int ot = 0; ot < 8; ++ot) {
        bf16x8 b = *reinterpret_cast<const bf16x8*>(
            &wlds[(((ks * 4 + quad) * 128) + ot * 16 + c16) * 8]);
        acc[0][ot] = __builtin_amdgcn_mfma_f32_16x16x32_bf16(b, af[0][ks], acc[0][ot], 0, 0, 0);
        acc[1][ot] = __builtin_amdgcn_mfma_f32_16x16x32_bf16(b, af[1][ks], acc[1][ot], 0, 0, 0);
      }
    }

#pragma unroll
    for (int h = 0; h < 2; ++h) {
      const int grow = base + wave * 32 + h * 16 + c16;
      const bool ok = grow < n;
      __hip_bfloat16* rp = xwout + (((size_t)r * n + grow) << 7) + quad * 4;
      float s_q = 0.f, s_k = 0.f;
#pragma unroll
      for (int ot = 0; ot < 8; ++ot) {
        f32x4 a = acc[h][ot];
        f32x4 q4 = *reinterpret_cast<const f32x4*>(&qls[ot * 16 + quad * 4]);
        f32x4 k4 = *reinterpret_cast<const f32x4*>(&kls[ot * 16 + quad * 4]);
        s_q += a[0] * q4[0] + a[1] * q4[1] + a[2] * q4[2] + a[3] * q4[3];
        s_k += a[0] * k4[0] + a[1] * k4[1] + a[2] * k4[2] + a[3] * k4[3];
        if (ok) {
          union { __hip_bfloat16 b4[4]; uint2 u; } pk;
#pragma unroll
          for (int t = 0; t < 4; ++t) pk.b4[t] = __float2bfloat16(a[t]);
          *reinterpret_cast<uint2*>(rp + ot * 16) = pk.u;
        }
      }
      s_q += __shfl_xor(s_q, 16, 64);
      s_q += __shfl_xor(s_q, 32, 64);
      s_k += __shfl_xor(s_k, 16, 64);
      s_k += __shfl_xor(s_k, 32, 64);
      if (quad == 0 && ok) {
        sq[(size_t)r * n + grow] = s_q;
        sk[(size_t)r * n + grow] = s_k;
      }
    }
  }
}

// ---------------- gemm1 + scatter fused (independent work, block-split) ------
// blocks [0, NT): gemm1 tiles (long pole first); blocks [NT, NT+eg4): scatter,
// 4 edges/thread.
__global__ __launch_bounds__(256) void gemm_scatter_kernel(
    const float* __restrict__ xin, const __hip_bfloat16* __restrict__ wt,
    const float* __restrict__ qv, const float* __restrict__ kv,
    __hip_bfloat16* __restrict__ xwout, float* __restrict__ sq, float* __restrict__ sk,
    const int* __restrict__ srcv, const int* __restrict__ dstv,
    const int* __restrict__ etype, const float* __restrict__ eattr,
    int* __restrict__ cursor, int2* __restrict__ kattr,
    int NT, int n, int E) {
  __shared__ __hip_bfloat16 wlds[16 * 128 * 8];  // 32 KB
  __shared__ float qls[128], kls[128];
  const int b = blockIdx.x;
  if (b < NT) {
    gemm_body128<0>(b, xin, nullptr, wt, qv, kv, xwout, sq, sk, n, wlds, qls, kls);
  } else {
    int e0 = (b - NT) * 1024 + threadIdx.x * 4;
    if (e0 + 3 < E) {
      int4 s4 = *reinterpret_cast<const int4*>(&srcv[e0]);
      int4 d4 = *reinterpret_cast<const int4*>(&dstv[e0]);
      int4 t4 = *reinterpret_cast<const int4*>(&etype[e0]);
      float4 a4 = *reinterpret_cast<const float4*>(&eattr[e0]);
      int p0 = atomicAdd(&cursor[d4.x], 1);
      kattr[p0] = make_int2(t4.x * n + s4.x, __float_as_int(a4.x));
      int p1 = atomicAdd(&cursor[d4.y], 1);
      kattr[p1] = make_int2(t4.y * n + s4.y, __float_as_int(a4.y));
      int p2 = atomicAdd(&cursor[d4.z], 1);
      kattr[p2] = make_int2(t4.z * n + s4.z, __float_as_int(a4.z));
      int p3 = atomicAdd(&cursor[d4.w], 1);
      kattr[p3] = make_int2(t4.w * n + s4.w, __float_as_int(a4.w));
    } else {
      for (int t = 0; t < 4; ++t) {
        int e = e0 + t;
        if (e < E) {
          int p = atomicAdd(&cursor[dstv[e]], 1);
          kattr[p] = make_int2(etype[e] * n + srcv[e], __float_as_int(eattr[e]));
        }
      }
    }
  }
}

// layer 2: bf16 input (hb)
__global__ __launch_bounds__(256) void gemm_xw_bf16_kernel(
    const __hip_bfloat16* __restrict__ xin, const __hip_bfloat16* __restrict__ wt,
    const float* __restrict__ qv, const float* __restrict__ kv,
    __hip_bfloat16* __restrict__ xwout, float* __restrict__ sq, float* __restrict__ sk,
    int n) {
  __shared__ __hip_bfloat16 wlds[16 * 128 * 8];
  __shared__ float qls[128], kls[128];
  gemm_body128<1>(blockIdx.x, nullptr, xin, wt, qv, kv, xwout, sq, sk, n,
                  wlds, qls, kls);
}

// ---------------- aggregation: one 16-lane group per node --------------------
// 4 nodes/wave, 16 nodes/block. den and acc lane-local (no reductions); all 16
// lanes write the output row. OUTBF16: layer-1 writes bf16+relu; layer-2 f32.
template <int OUTBF16>
__global__ __launch_bounds__(256) void aggregate_kernel(
    const int* __restrict__ rowptr, const int2* __restrict__ kattr,
    const float* __restrict__ sq, const float* __restrict__ sk,
    const __hip_bfloat16* __restrict__ xw, const float* __restrict__ bias,
    const float* __restrict__ cscal, float* __restrict__ outf,
    __hip_bfloat16* __restrict__ outb, int n) {
  const int wave = threadIdx.x >> 6, lane = threadIdx.x & 63;
  const int g = lane >> 4;     // node slot within wave
  const int sub = lane & 15;   // 8-col chunk within node row
  const int node = blockIdx.x * 16 + wave * 4 + g;
  if (node >= n) return;       // per-group predication; no barriers below
  const float c = cscal[0];
  const int n2 = n * 2;

  const int start = rowptr[node];
  const int deg = rowptr[node + 1] - start;
  const float s0 = sq[node], s1 = sq[n + node], s2 = sq[n2 + node];

  float acc[8];
#pragma unroll
  for (int t = 0; t < 8; ++t) acc[t] = 0.f;
  float den = 0.f;

  for (int j0 = 0; j0 < deg; j0 += 4) {
    // 4 independent gather chains (this group's node)
    int2 ka[4];
#pragma unroll
    for (int t = 0; t < 4; ++t) {
      int idx = j0 + t;
      ka[t] = kattr[start + (idx < deg ? idx : 0)];
    }
    float w[4];
    bf16x8 f[4];
#pragma unroll
    for (int t = 0; t < 4; ++t) {
      int kk = ka[t].x;
      float sv = (kk >= n2) ? s2 : ((kk >= n) ? s1 : s0);
      float l = sv + sk[kk] + c * __int_as_float(ka[t].y);
      l = l > 0.f ? l : 0.2f * l;
      w[t] = (j0 + t < deg) ? __expf(l) : 0.f;
      f[t] = *reinterpret_cast<const bf16x8*>(xw + ((size_t)kk << 7) + sub * 8);
    }
#pragma unroll
    for (int t = 0; t < 8; ++t)
      acc[t] += w[0] * (float)f[0][t] + w[1] * (float)f[1][t] +
                w[2] * (float)f[2][t] + w[3] * (float)f[3][t];
    den += (w[0] + w[1]) + (w[2] + w[3]);
  }

  float inv = 1.0f / (den + 1e-16f);
  f32x4 b0 = *reinterpret_cast<const f32x4*>(bias + sub * 8);
  f32x4 b1 = *reinterpret_cast<const f32x4*>(bias + sub * 8 + 4);
  f32x4 o0, o1;
#pragma unroll
  for (int t = 0; t < 4; ++t) {
    o0[t] = acc[t] * inv + b0[t];
    o1[t] = acc[4 + t] * inv + b1[t];
  }
  if (OUTBF16) {
    // relu + bf16 store (same rounding point as f32-store + later cvt)
    union { __hip_bfloat16 h[8]; int4 v; } pk;
#pragma unroll
    for (int t = 0; t < 4; ++t) {
      pk.h[t] = __float2bfloat16(fmaxf(o0[t], 0.f));
      pk.h[4 + t] = __float2bfloat16(fmaxf(o1[t], 0.f));
    }
    *reinterpret_cast<int4*>(outb + (size_t)node * CDIM + sub * 8) = pk.v;
  } else {
    float* op = outf + (size_t)node * CDIM + sub * 8;
    *reinterpret_cast<f32x4*>(op) = o0;
    *reinterpret_cast<f32x4*>(op + 4) = o1;
  }
}

// ---------------- launcher ----------------

extern "C" void kernel_launch(void* const* d_in, const int* in_sizes, int n_in,
                              void* d_out, int out_size, void* d_ws, size_t ws_size,
                              hipStream_t stream) {
  const float* x     = (const float*)d_in[0];
  const int*   eidx  = (const int*)d_in[1];
  const int*   etype = (const int*)d_in[2];
  const float* eattr = (const float*)d_in[3];
  const float* w1  = (const float*)d_in[4];
  const float* q1  = (const float*)d_in[5];
  const float* k1  = (const float*)d_in[6];
  const float* le1 = (const float*)d_in[7];
  const float* e1  = (const float*)d_in[8];
  const float* b1  = (const float*)d_in[9];
  const float* w2  = (const float*)d_in[10];
  const float* q2  = (const float*)d_in[11];
  const float* k2  = (const float*)d_in[12];
  const float* le2 = (const float*)d_in[13];
  const float* e2  = (const float*)d_in[14];
  const float* b2  = (const float*)d_in[15];

  const int N = in_sizes[0] / CDIM;           // 50000
  const int E = in_sizes[2];                  // 500000
  const int R = in_sizes[4] / (CDIM * CDIM);  // 3
  const int* srcv = eidx;
  const int* dstv = eidx + E;

  char* p = (char*)d_ws;
  auto alloc = [&](size_t bytes) -> void* {
    void* q = (void*)p;
    p += (bytes + 255) & ~(size_t)255;
    return q;
  };
  float* sq       = (float*)alloc((size_t)R * N * 4);
  float* sk       = (float*)alloc((size_t)R * N * 4);
  int*   deg      = (int*)alloc((size_t)N * 4);
  int*   rowptr   = (int*)alloc((size_t)(N + 1) * 4);
  int*   cursor   = (int*)alloc((size_t)N * 4);
  int*   partials = (int*)alloc(4096);
  int2*  kattr    = (int2*)alloc((size_t)E * 8);
  __hip_bfloat16* wt = (__hip_bfloat16*)alloc((size_t)2 * R * CDIM * CDIM * 2);
  float* cscal    = (float*)alloc(256);
  __hip_bfloat16* xw = (__hip_bfloat16*)alloc((size_t)R * N * CDIM * 2);
  __hip_bfloat16* hb = (__hip_bfloat16*)alloc((size_t)N * CDIM * 2);

  size_t needed = (size_t)(p - (char*)d_ws);
  if (needed > ws_size) {
    sentinel_kernel<<<1, 64, 0, stream>>>((float*)d_out);
    return;
  }

  float* outp = (float*)d_out;

  const int eg4 = (E + 1023) / 1024;          // 489 (4 edges/thread)
  const int nb = (N + 1023) / 1024;           // 49 (<=64 required by scan3 prefix)
  const int NT = (N + 127) / 128;             // 391 gemm tiles
  const int nodes16 = (N + 15) / 16;          // 3125 agg blocks
  const int perW = R * 2048;

  // 1) zero deg (stream-ordered, graph-capturable)
  hipMemsetAsync(deg, 0, (size_t)N * 4, stream);

  // 2) prep (wt transpose + consts) + hist, fused
  prep_hist_kernel<<<49 + eg4, 256, 0, stream>>>(w1, w2, wt, le1, e1, le2, e2,
                                                 cscal, dstv, deg, perW, E);

  // 3-4) CSR scans
  scan1_kernel<<<nb, 256, 0, stream>>>(deg, rowptr, partials, N);
  scan3_kernel<<<(N + 1 + 255) / 256, 256, 0, stream>>>(rowptr, cursor, partials, nb, N, E);

  // 5) gemm1 (blocks [0,NT)) + scatter (blocks [NT,NT+eg4)), fused
  gemm_scatter_kernel<<<NT + eg4, 256, 0, stream>>>(x, wt, q1, k1, xw, sq, sk,
                                                    srcv, dstv, etype, eattr,
                                                    cursor, kattr, NT, N, E);

  // 6) aggregate layer 1 -> bf16 hidden (relu)
  aggregate_kernel<1><<<nodes16, 256, 0, stream>>>(rowptr, kattr, sq, sk, xw, b1,
                                                   cscal + 0, nullptr, hb, N);

  // 7) gemm layer 2 (bf16 input)
  gemm_xw_bf16_kernel<<<NT, 256, 0, stream>>>(hb, wt + (size_t)R * CDIM * CDIM,
                                              q2, k2, xw, sq, sk, N);

  // 8) aggregate layer 2 -> f32 output
  aggregate_kernel<0><<<nodes16, 256, 0, stream>>>(rowptr, kattr, sq, sk, xw, b2,
                                                   cscal + 1, outp, nullptr, N);
}